// Round 11
// baseline (14850.319 us; speedup 1.0000x reference)
//
#include <hip/hip_runtime.h>
#include <stdint.h>

#define BDIM 256
#define SEQL 128
#define IND 512
#define HID 512
#define KDIM 1024 // IND + HID
#define NBLK 256u

typedef __bf16 bf16x8 __attribute__((ext_vector_type(8)));
typedef float floatx4 __attribute__((ext_vector_type(4)));

__device__ __forceinline__ float sigm(float x) { return 1.0f / (1.0f + __expf(-x)); }

// bf16 RNE split helpers (finite data only)
__device__ __forceinline__ ushort f2bf(float v) {
  uint32_t x = __builtin_bit_cast(uint32_t, v);
  x += 0x7fffu + ((x >> 16) & 1u);
  return (ushort)(x >> 16);
}
__device__ __forceinline__ float bf2f(ushort u) {
  return __builtin_bit_cast(float, ((uint32_t)u) << 16);
}

// ---- one-time: W -> bf16 hi/lo in [4H][IN|HID] row-major; combined bias ----
__global__ __launch_bounds__(256) void k_wconv(
    const float* __restrict__ W_ih, const float* __restrict__ W_hh,
    const float* __restrict__ b_ih, const float* __restrict__ b_hh,
    ushort* __restrict__ Whi, ushort* __restrict__ Wlo, float* __restrict__ bias) {
  int row = blockIdx.x;  // 0..2047 (torch order: i,f,g,o blocks of HID)
  if (threadIdx.x == 0) bias[row] = b_ih[row] + b_hh[row];
  for (int k = threadIdx.x; k < KDIM; k += 256) {
    float w = (k < IND) ? W_ih[(size_t)row * IND + k] : W_hh[(size_t)row * HID + (k - IND)];
    ushort hi = f2bf(w);
    Whi[(size_t)row * KDIM + k] = hi;
    Wlo[(size_t)row * KDIM + k] = f2bf(w - bf2f(hi));
  }
}

// ---- one-time: WaT[j][s] = Wa[s][j] (contiguous j-rows for partials) ----
__global__ void k_waT(const float* __restrict__ Wa, float* __restrict__ WaT) {
  int s = blockIdx.x;
  for (int j = threadIdx.x; j < HID; j += 256)
    WaT[(size_t)j * SEQL + s] = Wa[(size_t)s * HID + j];
}

// ---- init: h0,c0 from the zero-input zero-state cell (gates = bias) ----
__global__ void k_init(const float* __restrict__ b_ih, const float* __restrict__ b_hh,
                       float* __restrict__ c, ushort* __restrict__ Ahi, ushort* __restrict__ Alo) {
  int b = blockIdx.x;
  for (int j = threadIdx.x; j < HID; j += blockDim.x) {
    float bi = b_ih[j] + b_hh[j];
    float bg = b_ih[2 * HID + j] + b_hh[2 * HID + j];
    float bo = b_ih[3 * HID + j] + b_hh[3 * HID + j];
    float c0 = sigm(bi) * tanhf(bg);
    float h0 = sigm(bo) * tanhf(c0);
    c[b * HID + j] = c0;
    ushort hi = f2bf(h0);
    Ahi[(size_t)b * KDIM + IND + j] = hi;
    Alo[(size_t)b * KDIM + IND + j] = f2bf(h0 - bf2f(hi));
  }
}

struct AttnS { float sl[SEQL]; float sxi[2][HID]; };
struct GateS {
  ushort sA[2][2][16][72];   // [buf][hi/lo][batch][k] 9 KB
  ushort sW[2][2][64][72];   // [buf][hi/lo][g*16+jj][k] 36 KB
  float  sR[4][16][16];      // gate exchange 4 KB
  float  sC[16][16];         // cn tile for logit partials 1 KB
};
union SU { AttnS a; GateS g; };

// Flat grid barrier, R3-proven: RELEASE arrival (L2 writeback), RELAXED spin
// (no per-poll invalidate), one ACQUIRE after exit.
__device__ __forceinline__ void gbar(unsigned* cnt, unsigned* gen) {
  __syncthreads();
  if (threadIdx.x == 0) {
    unsigned g0 = __hip_atomic_load(gen, __ATOMIC_RELAXED, __HIP_MEMORY_SCOPE_AGENT);
    unsigned a = __hip_atomic_fetch_add(cnt, 1u, __ATOMIC_RELEASE, __HIP_MEMORY_SCOPE_AGENT);
    if (a == NBLK - 1u) {
      __hip_atomic_store(cnt, 0u, __ATOMIC_RELAXED, __HIP_MEMORY_SCOPE_AGENT);
      __hip_atomic_fetch_add(gen, 1u, __ATOMIC_ACQ_REL, __HIP_MEMORY_SCOPE_AGENT);
    } else {
      while (__hip_atomic_load(gen, __ATOMIC_RELAXED, __HIP_MEMORY_SCOPE_AGENT) == g0)
        __builtin_amdgcn_s_sleep(8);
      (void)__hip_atomic_load(gen, __ATOMIC_ACQUIRE, __HIP_MEMORY_SCOPE_AGENT);
    }
  }
  __syncthreads();
}

// gates staging/compute (R9 v3, proven): split accA/accB chains
#define G3LOAD(R, KO) do { \
  R##a  = *(const uint4*)(gA + (KO)); \
  R##w0 = *(const uint4*)(gWhi + (KO));      R##w1 = *(const uint4*)(gWhi + (KO) + 8);  \
  R##w2 = *(const uint4*)(gWlo + (KO));      R##w3 = *(const uint4*)(gWlo + (KO) + 8);  } while (0)
#define G3STORE(BUF, R) do { \
  *(uint4*)&sA[BUF][sthalf][ar][ac] = R##a; \
  *(uint4*)&sW[BUF][0][wr][wc] = R##w0;  *(uint4*)&sW[BUF][0][wr][wc + 8] = R##w1; \
  *(uint4*)&sW[BUF][1][wr][wc] = R##w2;  *(uint4*)&sW[BUF][1][wr][wc + 8] = R##w3; } while (0)
#define G3COMPUTE(BUF) do { \
  _Pragma("unroll") for (int ks = 0; ks < 2; ++ks) { \
    int kb = ks * 32 + koff; \
    bf16x8 ah = *(const bf16x8*)(&sA[BUF][0][ml][kb]); \
    bf16x8 al = *(const bf16x8*)(&sA[BUF][1][ml][kb]); \
    bf16x8 wh = *(const bf16x8*)(&sW[BUF][0][g * 16 + ml][kb]); \
    bf16x8 wl = *(const bf16x8*)(&sW[BUF][1][g * 16 + ml][kb]); \
    accA = __builtin_amdgcn_mfma_f32_16x16x32_bf16(ah, wh, accA, 0, 0, 0); \
    accB = __builtin_amdgcn_mfma_f32_16x16x32_bf16(ah, wl, accB, 0, 0, 0); \
    accB = __builtin_amdgcn_mfma_f32_16x16x32_bf16(al, wh, accB, 0, 0, 0); } } while (0)

// Persistent: x in VGPR (R8-proven), c in registers, logits via per-j-tile
// partials computed inside the gates phase. A activations DOUBLE-BUFFERED
// (R10's single-A raced: other blocks' GEMMs still read h_t while fast
// blocks wrote h_{t+1} into the same rows -> 8.8e-3 absmax). P2 writes xi
// into R=buf[t&1]; P3 reads R, writes h into D=buf[(t+1)&1].
__global__ __launch_bounds__(256, 1) void k_persist(
    const float* __restrict__ x, const float* __restrict__ WaT,
    const float* __restrict__ ba, float* __restrict__ out,
    const float* __restrict__ c0g, const float* __restrict__ bias,
    const ushort* __restrict__ Whi, const ushort* __restrict__ Wlo,
    ushort* __restrict__ A0hi, ushort* __restrict__ A0lo,
    ushort* __restrict__ A1hi, ushort* __restrict__ A1lo,
    float* __restrict__ part,
    unsigned* cnt, unsigned* gen) {
  __shared__ __align__(16) SU su;
  auto& sA = su.g.sA; auto& sW = su.g.sW;
  int blk = blockIdx.x, tid = threadIdx.x;
  int lane = tid & 63;

  // ---- x[blk] resident: thread owns (seq-half ph, d-quad cix) ----
  int cix = tid & 127, ph = tid >> 7;
  float4 xr[64];
  {
    const float* xbase = x + (size_t)blk * SEQL * IND + (size_t)ph * 64 * IND + 4 * cix;
#pragma unroll
    for (int i = 0; i < 64; ++i) xr[i] = *(const float4*)(xbase + (size_t)i * IND);
  }

  // ---- decode: XCD n covers j-tiles 4n..4n+3 (W slice ~1MB L2-resident) ----
  int n = blk & 7, m = blk >> 3;
  int b0 = (m & 15) * 16;
  int jt0 = 4 * n + (m >> 4);          // this block's j-tiles: jt0, jt0+2
  int sthalf = tid >> 7;
  int ar = (tid & 127) >> 3, ac = (tid & 7) * 8;
  int wr = tid >> 2, wc = (tid & 3) * 16;
  int g = tid >> 6, ml = lane & 15, koff = (lane >> 4) * 8;
  int jj = tid & 15, bb = tid >> 4;    // (j, batch) ownership; (s-group, batch) in partials

  auto partial_from_sC = [&](int jt, int j0) {
    float pv[8] = {0.f, 0.f, 0.f, 0.f, 0.f, 0.f, 0.f, 0.f};
#pragma unroll
    for (int j = 0; j < 16; ++j) {
      float cv = su.g.sC[bb][j];
      const float* wt = WaT + (size_t)(j0 + j) * SEQL + jj * 8;
#pragma unroll
      for (int k = 0; k < 8; ++k) pv[k] += cv * wt[k];
    }
    float* pd = part + ((size_t)jt * BDIM + (b0 + bb)) * SEQL + jj * 8;
#pragma unroll
    for (int k = 0; k < 8; ++k) pd[k] = pv[k];
  };

  // ---- prologue: c -> registers, initial logit partials from c0 ----
  float cReg[2];
#pragma unroll
  for (int t2 = 0; t2 < 2; ++t2) {
    int jt = jt0 + 2 * t2, j0 = jt * 16;
    float cv = c0g[(size_t)(b0 + bb) * HID + j0 + jj];
    cReg[t2] = cv;
    su.g.sC[bb][jj] = cv;
    __syncthreads();
    partial_from_sC(jt, j0);
    __syncthreads();
  }
  gbar(cnt, gen);

  for (int t = 0; t < SEQL; ++t) {
    ushort* Rhi = (t & 1) ? A1hi : A0hi;
    ushort* Rlo = (t & 1) ? A1lo : A0lo;
    ushort* Dhi = (t & 1) ? A0hi : A1hi;
    ushort* Dlo = (t & 1) ? A0lo : A1lo;

    // ========== P2: logits-sum + softmax + xi(from xr) + A write ==========
    if (tid < SEQL) {
      float acc = ba[tid];
      const float* pb = part + (size_t)blk * SEQL + tid;
#pragma unroll
      for (int jt = 0; jt < 32; ++jt) acc += pb[(size_t)jt * BDIM * SEQL];
      su.a.sl[tid] = acc;
    }
    __syncthreads();
    if (tid < 64) {
      float v0 = su.a.sl[tid], v1 = su.a.sl[tid + 64];
      float mx = fmaxf(v0, v1);
#pragma unroll
      for (int off = 32; off > 0; off >>= 1) mx = fmaxf(mx, __shfl_xor(mx, off));
      float e0 = __expf(v0 - mx), e1 = __expf(v1 - mx);
      float s2 = e0 + e1;
#pragma unroll
      for (int off = 32; off > 0; off >>= 1) s2 += __shfl_xor(s2, off);
      float inv = 1.f / s2;
      su.a.sl[tid] = e0 * inv; su.a.sl[tid + 64] = e1 * inv;
    }
    __syncthreads();
    {
      float4 aE = {0.f, 0.f, 0.f, 0.f}, aO = {0.f, 0.f, 0.f, 0.f};
#pragma unroll
      for (int i = 0; i < 64; i += 2) {
        float w0 = su.a.sl[ph * 64 + i];
        float w1 = su.a.sl[ph * 64 + i + 1];
        float4 v0 = xr[i], v1 = xr[i + 1];
        aE.x += w0 * v0.x; aE.y += w0 * v0.y; aE.z += w0 * v0.z; aE.w += w0 * v0.w;
        aO.x += w1 * v1.x; aO.y += w1 * v1.y; aO.z += w1 * v1.z; aO.w += w1 * v1.w;
      }
      float4 a4 = {aE.x + aO.x, aE.y + aO.y, aE.z + aO.z, aE.w + aO.w};
      *(float4*)(&su.a.sxi[ph][4 * cix]) = a4;
      __syncthreads();
      float rx = su.a.sxi[0][2 * tid] + su.a.sxi[1][2 * tid];
      float ry = su.a.sxi[0][2 * tid + 1] + su.a.sxi[1][2 * tid + 1];
      ushort hx = f2bf(rx), hy = f2bf(ry);
      uint hp = (uint)hx | ((uint)hy << 16);
      uint lp = (uint)f2bf(rx - bf2f(hx)) | ((uint)f2bf(ry - bf2f(hy)) << 16);
      *(uint*)(Rhi + (size_t)blk * KDIM + 2 * tid) = hp;
      *(uint*)(Rlo + (size_t)blk * KDIM + 2 * tid) = lp;
    }
    gbar(cnt, gen);

    // ========== P3: gates x2 j-tiles + reg-cell + h->D + next partials =====
#pragma unroll
    for (int t2 = 0; t2 < 2; ++t2) {
      int jt = jt0 + 2 * t2, j0 = jt * 16;
      const ushort* gA = (sthalf ? Rlo : Rhi) + (size_t)(b0 + ar) * KDIM + ac;
      int wrow = (wr >> 4) * HID + j0 + (wr & 15);
      const ushort* gWhi = Whi + (size_t)wrow * KDIM + wc;
      const ushort* gWlo = Wlo + (size_t)wrow * KDIM + wc;
      floatx4 accA = {0.f, 0.f, 0.f, 0.f}, accB = {0.f, 0.f, 0.f, 0.f};
      uint4 Aa, Aw0, Aw1, Aw2, Aw3, Ba, Bw0, Bw1, Bw2, Bw3;
      G3LOAD(A, 0); G3LOAD(B, 64);
      G3STORE(0, A); G3STORE(1, B);
      G3LOAD(A, 128); G3LOAD(B, 192);
      __syncthreads();
      for (int k0 = 0; k0 < 16; k0 += 2) {
        G3COMPUTE(0);
        __syncthreads();
        if (k0 + 2 < 16) { G3STORE(0, A); if (k0 + 4 < 16) G3LOAD(A, (k0 + 4) * 64); }
        G3COMPUTE(1);
        __syncthreads();
        if (k0 + 3 < 16) { G3STORE(1, B); if (k0 + 5 < 16) G3LOAD(B, (k0 + 5) * 64); }
      }
      {
        floatx4 acc = accA + accB;
#pragma unroll
        for (int r = 0; r < 4; ++r) su.g.sR[g][ml][(lane >> 4) * 4 + r] = acc[r];
      }
      __syncthreads();
      {
        int jg = j0 + jj, b = b0 + bb;
        float ig = sigm(su.g.sR[0][jj][bb] + bias[jg]);
        float fg = sigm(su.g.sR[1][jj][bb] + bias[HID + jg]);
        float gg = tanhf(su.g.sR[2][jj][bb] + bias[2 * HID + jg]);
        float og = sigm(su.g.sR[3][jj][bb] + bias[3 * HID + jg]);
        float cn = fg * cReg[t2] + ig * gg;
        float hv = og * tanhf(cn);
        cReg[t2] = cn;
        out[((size_t)b * SEQL + t) * HID + jg] = hv;
        ushort hi = f2bf(hv);
        Dhi[(size_t)b * KDIM + IND + jg] = hi;
        Dlo[(size_t)b * KDIM + IND + jg] = f2bf(hv - bf2f(hi));
        su.g.sC[bb][jj] = cn;
      }
      __syncthreads();
      partial_from_sC(jt, j0);
      __syncthreads();
    }
    gbar(cnt, gen);
  }
}

extern "C" void kernel_launch(void* const* d_in, const int* in_sizes, int n_in,
                              void* d_out, int out_size, void* d_ws, size_t ws_size,
                              hipStream_t stream) {
  (void)in_sizes; (void)n_in; (void)out_size; (void)ws_size;
  const float* x    = (const float*)d_in[0];
  const float* W_ih = (const float*)d_in[1];
  const float* W_hh = (const float*)d_in[2];
  const float* b_ih = (const float*)d_in[3];
  const float* b_hh = (const float*)d_in[4];
  const float* Wa   = (const float*)d_in[5];
  const float* ba   = (const float*)d_in[6];
  float* out = (float*)d_out;

  // ws footprint: ~16 MiB
  char* p = (char*)d_ws;
  auto carve = [&](size_t bytes) { char* r = p; p += (bytes + 255) & ~(size_t)255; return r; };
  unsigned* bar = (unsigned*)carve(512);           // [0]=cnt, [64]=gen
  float*  c    = (float*)carve((size_t)BDIM * HID * 4);
  float*  bias = (float*)carve((size_t)4 * HID * 4);
  ushort* Whi  = (ushort*)carve((size_t)4 * HID * KDIM * 2);
  ushort* Wlo  = (ushort*)carve((size_t)4 * HID * KDIM * 2);
  ushort* A0hi = (ushort*)carve((size_t)BDIM * KDIM * 2);
  ushort* A0lo = (ushort*)carve((size_t)BDIM * KDIM * 2);
  ushort* A1hi = (ushort*)carve((size_t)BDIM * KDIM * 2);
  ushort* A1lo = (ushort*)carve((size_t)BDIM * KDIM * 2);
  float*  WaT  = (float*)carve((size_t)HID * SEQL * 4);
  float*  part = (float*)carve((size_t)32 * BDIM * SEQL * 4);

  hipMemsetAsync(bar, 0, 512, stream);
  k_wconv<<<4 * HID, 256, 0, stream>>>(W_ih, W_hh, b_ih, b_hh, Whi, Wlo, bias);
  k_waT<<<SEQL, 256, 0, stream>>>(Wa, WaT);
  k_init<<<BDIM, 256, 0, stream>>>(b_ih, b_hh, c, A0hi, A0lo);
  k_persist<<<NBLK, 256, 0, stream>>>(x, WaT, ba, out, c, bias, Whi, Wlo,
                                      A0hi, A0lo, A1hi, A1lo, part, bar, bar + 64);
}

// Round 12
// 4707.327 us; speedup vs baseline: 3.1547x; 3.1547x over previous
//
#include <hip/hip_runtime.h>
#include <stdint.h>

#define BDIM 256
#define SEQL 128
#define IND 512
#define HID 512
#define KDIM 1024 // IND + HID

typedef __bf16 bf16x8 __attribute__((ext_vector_type(8)));
typedef float floatx4 __attribute__((ext_vector_type(4)));
typedef _Float16 f16x8 __attribute__((ext_vector_type(8)));

__device__ __forceinline__ float sigm(float x) { return 1.0f / (1.0f + __expf(-x)); }

// bf16 RNE split helpers (finite data only)
__device__ __forceinline__ ushort f2bf(float v) {
  uint32_t x = __builtin_bit_cast(uint32_t, v);
  x += 0x7fffu + ((x >> 16) & 1u);
  return (ushort)(x >> 16);
}
__device__ __forceinline__ float bf2f(ushort u) {
  return __builtin_bit_cast(float, ((uint32_t)u) << 16);
}

// ---- one-time: W -> bf16 hi/lo in [4H][IN|HID] row-major; combined bias ----
__global__ __launch_bounds__(256) void k_wconv(
    const float* __restrict__ W_ih, const float* __restrict__ W_hh,
    const float* __restrict__ b_ih, const float* __restrict__ b_hh,
    ushort* __restrict__ Whi, ushort* __restrict__ Wlo, float* __restrict__ bias) {
  int row = blockIdx.x;  // 0..2047 (torch order: i,f,g,o blocks of HID)
  if (threadIdx.x == 0) bias[row] = b_ih[row] + b_hh[row];
  for (int k = threadIdx.x; k < KDIM; k += 256) {
    float w = (k < IND) ? W_ih[(size_t)row * IND + k] : W_hh[(size_t)row * HID + (k - IND)];
    ushort hi = f2bf(w);
    Whi[(size_t)row * KDIM + k] = hi;
    Wlo[(size_t)row * KDIM + k] = f2bf(w - bf2f(hi));
  }
}

// ---- one-time: x -> fp16 (RNE). Halves the per-step xi stream: the R7/R8/
// R11 arc proved xi is BW-bound on the 67 MB/step x re-read (can't be hidden
// by concurrency, can't be register-cached: xr[64]x4 spills -- R11's 11.9 GB
// FETCH). fp16 err 2.4e-4 rel; xi err ~2e-4 abs -> gate err ~1.4e-4, safe.
__global__ __launch_bounds__(256) void k_xconv(const float* __restrict__ x,
                                               _Float16* __restrict__ xh) {
  size_t i = ((size_t)blockIdx.x * 256 + threadIdx.x) * 8;
  float4 v0 = *(const float4*)(x + i);
  float4 v1 = *(const float4*)(x + i + 4);
  f16x8 o;
  o[0] = (_Float16)v0.x; o[1] = (_Float16)v0.y; o[2] = (_Float16)v0.z; o[3] = (_Float16)v0.w;
  o[4] = (_Float16)v1.x; o[5] = (_Float16)v1.y; o[6] = (_Float16)v1.z; o[7] = (_Float16)v1.w;
  *(f16x8*)(xh + i) = o;
}

// ---- init: h0,c0 from the zero-input zero-state cell (gates = bias) ----
__global__ void k_init(const float* __restrict__ b_ih, const float* __restrict__ b_hh,
                       float* __restrict__ c, ushort* __restrict__ Ahi, ushort* __restrict__ Alo) {
  int b = blockIdx.x;
  for (int j = threadIdx.x; j < HID; j += blockDim.x) {
    float bi = b_ih[j] + b_hh[j];
    float bg = b_ih[2 * HID + j] + b_hh[2 * HID + j];
    float bo = b_ih[3 * HID + j] + b_hh[3 * HID + j];
    float c0 = sigm(bi) * tanhf(bg);
    float h0 = sigm(bo) * tanhf(c0);
    c[b * HID + j] = c0;
    ushort hi = f2bf(h0);
    Ahi[(size_t)b * KDIM + IND + j] = hi;
    Alo[(size_t)b * KDIM + IND + j] = f2bf(h0 - bf2f(hi));
  }
}

// ---- per step: attention logits -> softmax -> xi(fp16 x) -> A write ----
__global__ __launch_bounds__(256) void k_attn(const float* __restrict__ c, const float* __restrict__ Wa,
                                              const float* __restrict__ ba, const _Float16* __restrict__ xh,
                                              ushort* __restrict__ Ahi, ushort* __restrict__ Alo) {
  __shared__ float sc[HID];
  __shared__ float sl[SEQL];
  __shared__ float sxi[4][HID];
  int b = blockIdx.x, tid = threadIdx.x;
  sc[tid] = c[b * HID + tid];
  sc[tid + 256] = c[b * HID + tid + 256];
  __syncthreads();
  int wave = tid >> 6, lane = tid & 63;
  // logits (R6-proven): reg-hoisted c fragment, float4 Wa, unroll-4 rows
  float4 c0 = *(const float4*)(&sc[lane * 4]);
  float4 c1 = *(const float4*)(&sc[lane * 4 + 256]);
#pragma unroll 4
  for (int si = 0; si < 32; ++si) {
    int s = wave * 32 + si;
    const float4* wr = (const float4*)(Wa + (size_t)s * HID);
    float4 w0 = wr[lane];
    float4 w1 = wr[lane + 64];
    float acc = c0.x * w0.x + c0.y * w0.y + c0.z * w0.z + c0.w * w0.w
              + c1.x * w1.x + c1.y * w1.y + c1.z * w1.z + c1.w * w1.w;
#pragma unroll
    for (int off = 32; off > 0; off >>= 1) acc += __shfl_down(acc, off);
    if (lane == 0) sl[s] = acc + ba[s];
  }
  __syncthreads();
  if (tid < 64) {
    float v0 = sl[tid], v1 = sl[tid + 64];
    float m = fmaxf(v0, v1);
#pragma unroll
    for (int off = 32; off > 0; off >>= 1) m = fmaxf(m, __shfl_xor(m, off));
    float e0 = __expf(v0 - m), e1 = __expf(v1 - m);
    float s2 = e0 + e1;
#pragma unroll
    for (int off = 32; off > 0; off >>= 1) s2 += __shfl_xor(s2, off);
    float inv = 1.f / s2;
    sl[tid] = e0 * inv; sl[tid + 64] = e1 * inv;
  }
  __syncthreads();
  // xi: fp16 loads, 8 cols (16B) per thread, seq split in quarters (32 s);
  // 8 independent FMA chains, unroll-8 keeps many 16B loads in flight
  int cix = tid & 63;   // col-oct: cols 8*cix .. +7
  int qp = tid >> 6;    // seq quarter
  const _Float16* xrow = xh + (size_t)b * SEQL * IND + (size_t)qp * 32 * IND + 8 * cix;
  float a0 = 0.f, a1 = 0.f, a2 = 0.f, a3 = 0.f, a4 = 0.f, a5 = 0.f, a6 = 0.f, a7 = 0.f;
#pragma unroll 8
  for (int s = 0; s < 32; ++s) {
    float w = sl[qp * 32 + s];
    f16x8 v = *(const f16x8*)(xrow + (size_t)s * IND);
    a0 += w * (float)v[0]; a1 += w * (float)v[1];
    a2 += w * (float)v[2]; a3 += w * (float)v[3];
    a4 += w * (float)v[4]; a5 += w * (float)v[5];
    a6 += w * (float)v[6]; a7 += w * (float)v[7];
  }
  *(float4*)(&sxi[qp][8 * cix])     = (float4){a0, a1, a2, a3};
  *(float4*)(&sxi[qp][8 * cix + 4]) = (float4){a4, a5, a6, a7};
  __syncthreads();
  float rx = sxi[0][2 * tid] + sxi[1][2 * tid] + sxi[2][2 * tid] + sxi[3][2 * tid];
  float ry = sxi[0][2 * tid + 1] + sxi[1][2 * tid + 1] + sxi[2][2 * tid + 1] + sxi[3][2 * tid + 1];
  ushort hx = f2bf(rx), hy = f2bf(ry);
  uint hp = (uint)hx | ((uint)hy << 16);
  uint lp = (uint)f2bf(rx - bf2f(hx)) | ((uint)f2bf(ry - bf2f(hy)) << 16);
  *(uint*)(Ahi + (size_t)b * KDIM + 2 * tid) = hp;
  *(uint*)(Alo + (size_t)b * KDIM + 2 * tid) = lp;
}

// ---- per step: gates GEMM v3 (R9-proven): 512 blocks (2/CU, 8 waves/CU),
// 16-batch x 64-row tiles, wave g owns gate g, split accA/accB chains.
#define G3LOAD(R, KO) do { \
  R##a  = *(const uint4*)(gA + (KO)); \
  R##w0 = *(const uint4*)(gWhi + (KO));      R##w1 = *(const uint4*)(gWhi + (KO) + 8);  \
  R##w2 = *(const uint4*)(gWlo + (KO));      R##w3 = *(const uint4*)(gWlo + (KO) + 8);  } while (0)
#define G3STORE(BUF, R) do { \
  *(uint4*)&sA[BUF][sthalf][ar][ac] = R##a; \
  *(uint4*)&sW[BUF][0][wr][wc] = R##w0;  *(uint4*)&sW[BUF][0][wr][wc + 8] = R##w1; \
  *(uint4*)&sW[BUF][1][wr][wc] = R##w2;  *(uint4*)&sW[BUF][1][wr][wc + 8] = R##w3; } while (0)
#define G3COMPUTE(BUF) do { \
  _Pragma("unroll") for (int ks = 0; ks < 2; ++ks) { \
    int kb = ks * 32 + koff; \
    bf16x8 ah = *(const bf16x8*)(&sA[BUF][0][ml][kb]); \
    bf16x8 al = *(const bf16x8*)(&sA[BUF][1][ml][kb]); \
    bf16x8 wh = *(const bf16x8*)(&sW[BUF][0][g * 16 + ml][kb]); \
    bf16x8 wl = *(const bf16x8*)(&sW[BUF][1][g * 16 + ml][kb]); \
    accA = __builtin_amdgcn_mfma_f32_16x16x32_bf16(ah, wh, accA, 0, 0, 0); \
    accB = __builtin_amdgcn_mfma_f32_16x16x32_bf16(ah, wl, accB, 0, 0, 0); \
    accB = __builtin_amdgcn_mfma_f32_16x16x32_bf16(al, wh, accB, 0, 0, 0); } } while (0)

__global__ __launch_bounds__(256) void k_gates(
    const ushort* __restrict__ Whi, const ushort* __restrict__ Wlo,
    const float* __restrict__ bias,
    const ushort* __restrict__ Ahi, const ushort* __restrict__ Alo,
    float* __restrict__ c, float* __restrict__ out,
    ushort* __restrict__ Dhi, ushort* __restrict__ Dlo, int tstep) {
  // XCD map: bid&7 = XCD n -> j-tiles 4n..4n+3 (W slice 1MB L2-resident)
  int bid = blockIdx.x;
  int lb = (bid & 7) * 64 + (bid >> 3);
  int j0 = (lb >> 4) * 16;   // 32 j-tiles
  int b0 = (lb & 15) * 16;   // 16 batch-tiles

  __shared__ __align__(16) ushort sA[2][2][16][72];  // [buf][hi/lo][batch][k] 9 KB
  __shared__ __align__(16) ushort sW[2][2][64][72];  // [buf][hi/lo][row][k] 36 KB
  __shared__ float sR[4][16][16];                    // [gate][j][b] exchange 4 KB

  int tid = threadIdx.x;
  int sthalf = tid >> 7;
  int ar = (tid & 127) >> 3;       // 0..15 batch row
  int ac = (tid & 7) * 8;          // col elems (16B)
  const ushort* gA = (sthalf ? Alo : Ahi) + (size_t)(b0 + ar) * KDIM + ac;
  int wr = tid >> 2;               // 0..63 row-in-tile
  int wc = (tid & 3) * 16;         // col elems
  int wrow = (wr >> 4) * HID + j0 + (wr & 15);  // global W row g*512+j
  const ushort* gWhi = Whi + (size_t)wrow * KDIM + wc;
  const ushort* gWlo = Wlo + (size_t)wrow * KDIM + wc;

  floatx4 accA = {0.f, 0.f, 0.f, 0.f}, accB = {0.f, 0.f, 0.f, 0.f};
  int lane = tid & 63, g = tid >> 6;
  int ml = lane & 15;
  int koff = (lane >> 4) * 8;

  uint4 Aa, Aw0, Aw1, Aw2, Aw3;
  uint4 Ba, Bw0, Bw1, Bw2, Bw3;

  G3LOAD(A, 0);
  G3LOAD(B, 64);
  G3STORE(0, A);
  G3STORE(1, B);
  G3LOAD(A, 128);
  G3LOAD(B, 192);
  __syncthreads();

  for (int k0 = 0; k0 < 16; k0 += 2) {
    G3COMPUTE(0);
    __syncthreads();
    if (k0 + 2 < 16) {
      G3STORE(0, A);
      if (k0 + 4 < 16) G3LOAD(A, (k0 + 4) * 64);
    }
    G3COMPUTE(1);
    __syncthreads();
    if (k0 + 3 < 16) {
      G3STORE(1, B);
      if (k0 + 5 < 16) G3LOAD(B, (k0 + 5) * 64);
    }
  }

  {
    floatx4 acc = accA + accB;
#pragma unroll
    for (int r = 0; r < 4; ++r) sR[g][ml][(lane >> 4) * 4 + r] = acc[r];
  }
  __syncthreads();

  {
    int jj = tid & 15, bb = tid >> 4;
    int jg = j0 + jj;
    int b = b0 + bb;
    float ig = sigm(sR[0][jj][bb] + bias[jg]);
    float fg = sigm(sR[1][jj][bb] + bias[HID + jg]);
    float gg = tanhf(sR[2][jj][bb] + bias[2 * HID + jg]);
    float og = sigm(sR[3][jj][bb] + bias[3 * HID + jg]);
    float co = c[b * HID + jg];
    float cn = fg * co + ig * gg;
    float hv = og * tanhf(cn);
    c[b * HID + jg] = cn;
    out[((size_t)b * SEQL + tstep) * HID + jg] = hv;
    ushort hi = f2bf(hv);
    Dhi[(size_t)b * KDIM + IND + jg] = hi;
    Dlo[(size_t)b * KDIM + IND + jg] = f2bf(hv - bf2f(hi));
  }
}

extern "C" void kernel_launch(void* const* d_in, const int* in_sizes, int n_in,
                              void* d_out, int out_size, void* d_ws, size_t ws_size,
                              hipStream_t stream) {
  (void)in_sizes; (void)n_in; (void)out_size; (void)ws_size;
  const float* x    = (const float*)d_in[0];
  const float* W_ih = (const float*)d_in[1];
  const float* W_hh = (const float*)d_in[2];
  const float* b_ih = (const float*)d_in[3];
  const float* b_hh = (const float*)d_in[4];
  const float* Wa   = (const float*)d_in[5];
  const float* ba   = (const float*)d_in[6];
  float* out = (float*)d_out;

  // ws footprint: ~44 MiB (xh = 32 MiB fp16 copy of x)
  char* p = (char*)d_ws;
  auto carve = [&](size_t bytes) { char* r = p; p += (bytes + 255) & ~(size_t)255; return r; };
  float*  c    = (float*)carve((size_t)BDIM * HID * 4);
  float*  bias = (float*)carve((size_t)4 * HID * 4);
  ushort* Whi  = (ushort*)carve((size_t)4 * HID * KDIM * 2);
  ushort* Wlo  = (ushort*)carve((size_t)4 * HID * KDIM * 2);
  ushort* A0hi = (ushort*)carve((size_t)BDIM * KDIM * 2);
  ushort* A0lo = (ushort*)carve((size_t)BDIM * KDIM * 2);
  ushort* A1hi = (ushort*)carve((size_t)BDIM * KDIM * 2);
  ushort* A1lo = (ushort*)carve((size_t)BDIM * KDIM * 2);
  _Float16* xh = (_Float16*)carve((size_t)BDIM * SEQL * IND * 2);

  k_wconv<<<4 * HID, 256, 0, stream>>>(W_ih, W_hh, b_ih, b_hh, Whi, Wlo, bias);
  k_xconv<<<(BDIM * SEQL * IND) / (256 * 8), 256, 0, stream>>>(x, xh);
  k_init<<<BDIM, 256, 0, stream>>>(b_ih, b_hh, c, A0hi, A0lo);

  for (int t = 0; t < SEQL; ++t) {
    ushort* Rhi = (t & 1) ? A1hi : A0hi;
    ushort* Rlo = (t & 1) ? A1lo : A0lo;
    ushort* Dhi = (t & 1) ? A0hi : A1hi;
    ushort* Dlo = (t & 1) ? A0lo : A1lo;
    k_attn<<<BDIM, 256, 0, stream>>>(c, Wa, ba, xh, Rhi, Rlo);
    k_gates<<<512, 256, 0, stream>>>(Whi, Wlo, bias, Rhi, Rlo, c, out, Dhi, Dlo, t);
  }
}